// Round 3
// baseline (2526.286 us; speedup 1.0000x reference)
//
#include <hip/hip_runtime.h>
#include <math.h>

#define NTOK   2048
#define D      512
#define NV     100000

typedef __attribute__((ext_vector_type(8)))  short bf16x8;
typedef __attribute__((ext_vector_type(16))) float f32x16;

// ---- workspace layout (bytes) ----
#define WS_FRAGS 0u          // 4 segs * 2048 rows * 512 * 2B = 8,388,608
#define WS_LISTS 8388608u    // 4 * 2048 * 4B
#define WS_ACC   8421376u    // 4 * 2049 * 4B = 32784  (zeroed each call, + cursors)
#define WS_CUR   8454160u    // 4 * 4
#define WS_PAD   8454176u    // 4 * 4
#define WS_CL    8454192u    // 2048 * 3 * 4B
#define WS_TGT   8478768u    // 2048 * 4B

__device__ __forceinline__ int cluster_of(int t){
  return (t < 10000) ? 0 : (t < 20000) ? 1 : (t < 50000) ? 2 : 3;
}
__device__ __forceinline__ bool is_root(int c){
  return c==5 || c==17 || c==123 || c==10005 || c==20007 || c==50011;
}
// f32 -> bf16 round-to-nearest-even
__device__ __forceinline__ unsigned short f2bf(float f){
  unsigned int u = __float_as_uint(f);
  u += 0x7fffu + ((u >> 16) & 1u);
  return (unsigned short)(u >> 16);
}

// ---------------------------------------------------------------------------
// K1: per-token cluster logits (3 dots) + exact-f32 target logit. 1 wave/token.
// ---------------------------------------------------------------------------
__global__ void k_token_logits(const float* __restrict__ hidden,
                               const float* __restrict__ weight,
                               const float* __restrict__ bias,
                               const float* __restrict__ cw,
                               const float* __restrict__ cb,
                               const int*   __restrict__ target,
                               float* __restrict__ cl_out,   // [2048][3]
                               float* __restrict__ tgt_out)  // [2048]
{
  int wave = threadIdx.x >> 6;
  int lane = threadIdx.x & 63;
  int n = blockIdx.x * 4 + wave;
  if (n >= NTOK) return;
  const float* h = hidden + (size_t)n * D + lane * 8;
  int t = target[n];
  const float* wt = weight + (size_t)t * D + lane * 8;
  float hv[8];
  #pragma unroll
  for (int i = 0; i < 8; ++i) hv[i] = h[i];
  float acc[4] = {0.f, 0.f, 0.f, 0.f};
  #pragma unroll
  for (int j = 0; j < 3; ++j){
    const float* cwj = cw + j * D + lane * 8;
    float s = 0.f;
    #pragma unroll
    for (int i = 0; i < 8; ++i) s += hv[i] * cwj[i];
    acc[j] = s;
  }
  {
    float s = 0.f;
    #pragma unroll
    for (int i = 0; i < 8; ++i) s += hv[i] * wt[i];
    acc[3] = s;
  }
  #pragma unroll
  for (int m = 1; m < 64; m <<= 1){
    #pragma unroll
    for (int j = 0; j < 4; ++j) acc[j] += __shfl_xor(acc[j], m, 64);
  }
  if (lane == 0){
    cl_out[n*3+0] = acc[0] + cb[0];
    cl_out[n*3+1] = acc[1] + cb[1];
    cl_out[n*3+2] = acc[2] + cb[2];
    float tg = acc[3] + bias[t];
    if (is_root(t)) tg = -INFINITY;
    tgt_out[n] = tg;
  }
}

// ---------------------------------------------------------------------------
// K2: build per-segment token lists. seg0 = identity; tails via atomic cursor.
// ---------------------------------------------------------------------------
__global__ void k_build_lists(const int* __restrict__ target,
                              int* __restrict__ lists, int* __restrict__ cursors)
{
  int n = blockIdx.x * blockDim.x + threadIdx.x;
  if (n >= NTOK) return;
  lists[n] = n;  // seg 0 identity
  int c = cluster_of(target[n]);
  if (c > 0){
    int pos = atomicAdd(cursors + c, 1);
    lists[c * 2048 + pos] = n;
  }
}

// ---------------------------------------------------------------------------
// K3: pad lists to multiples of 256 with sentinel token (=NTOK), write counts.
// ---------------------------------------------------------------------------
__global__ void k_pad_lists(int* __restrict__ lists, const int* __restrict__ cursors,
                            int* __restrict__ padded)
{
  if (threadIdx.x == 0) padded[0] = NTOK;
  for (int s = 1; s < 4; ++s){
    int c = cursors[s];
    int p = (c + 255) & ~255;
    if (threadIdx.x == 0) padded[s] = p;
    for (int i = c + threadIdx.x; i < p; i += blockDim.x)
      lists[s * 2048 + i] = NTOK;
  }
}

// ---------------------------------------------------------------------------
// K4: build bf16 A-fragments in MFMA-native layout per segment.
// elem offset = ((mf*32 + ks)*64 + lane)*8 ; row = mf*32+(lane&31),
// k = ks*16 + (lane>>5)*8 + j  (same k-convention as B).
// ---------------------------------------------------------------------------
__global__ void k_build_frags(const float* __restrict__ hidden,
                              const int*   __restrict__ lists,
                              const int*   __restrict__ padded,
                              unsigned short* __restrict__ frags)
{
  int tg   = blockIdx.x * 256 + threadIdx.x;   // [0, 4*131072)
  int seg  = tg >> 17;
  int s    = tg & 131071;
  int lane = s & 63;
  int ks   = (s >> 6) & 31;
  int mf   = s >> 11;
  int row  = mf * 32 + (lane & 31);
  if (row >= padded[seg]) return;
  int token = lists[seg * 2048 + row];
  unsigned int w[4];
  if (token < NTOK){
    const float* h = hidden + (size_t)token * D + ks * 16 + (lane >> 5) * 8;
    #pragma unroll
    for (int i = 0; i < 4; ++i){
      unsigned short lo = f2bf(h[2*i]);
      unsigned short hi = f2bf(h[2*i+1]);
      w[i] = (unsigned int)lo | ((unsigned int)hi << 16);
    }
  } else {
    w[0] = w[1] = w[2] = w[3] = 0u;
  }
  size_t off = ((size_t)seg * 2048 * 512) + (((size_t)(mf * 32 + ks)) * 64 + lane) * 8;
  uint4 val; val.x = w[0]; val.y = w[1]; val.z = w[2]; val.w = w[3];
  *(uint4*)(frags + off) = val;
}

// ---------------------------------------------------------------------------
// K5: Σexp GEMM, 32-col strips. B in frag-native LDS order (32 KB):
// byte off = ks*1024 + lane*16 (+ small XOR), so each wave's ds_read_b128 is a
// contiguous 1 KB block (conflict-free) at one base reg + imm offset.
// 4-deep explicit register prefetch pipeline, fully unrolled K loop.
// Epilogue: exp(logit+bias), 32-lane butterfly row-sum, atomicAdd per row.
// ---------------------------------------------------------------------------
__device__ __forceinline__ void epi32(const f32x16& a, float b0v, int rbase,
                                      int hi, int laneM,
                                      const int* __restrict__ lists_seg,
                                      float* __restrict__ acc_seg)
{
  float ev[16];
  #pragma unroll
  for (int r = 0; r < 16; ++r) ev[r] = __expf(a[r] + b0v);
  #pragma unroll
  for (int m = 1; m < 32; m <<= 1){
    #pragma unroll
    for (int r = 0; r < 16; ++r) ev[r] += __shfl_xor(ev[r], m, 64);
  }
  if (laneM == 0){
    #pragma unroll
    for (int r = 0; r < 16; ++r){
      int row = rbase + (r & 3) + 8 * (r >> 2) + 4 * hi;  // verified C/D layout
      atomicAdd(acc_seg + lists_seg[row], ev[r]);
    }
  }
}

__global__ __launch_bounds__(256, 4)
void k_gemm(const unsigned short* __restrict__ frags,
            const float* __restrict__ weight,
            const float* __restrict__ bias,
            const int*   __restrict__ lists,
            const int*   __restrict__ padded,
            float* __restrict__ acc_out)       // [4][2049]
{
  __shared__ unsigned short Bs[512 * 32];      // 32 KB

  int bid = blockIdx.x;
  int seg, strip0, colstart, colend;
  if      (bid < 313) { seg = 0; strip0 = 0;    colstart = 0;     colend = 10000;  }
  else if (bid < 626) { seg = 1; strip0 = 313;  colstart = 10000; colend = 20000;  }
  else if (bid < 1564){ seg = 2; strip0 = 626;  colstart = 20000; colend = 50000;  }
  else                { seg = 3; strip0 = 1564; colstart = 50000; colend = 100000; }
  int col_base = colstart + (bid - strip0) * 32;
  int col_end  = min(col_base + 32, colend);

  // ---- load B strip: 32 cols x 512 k, f32 -> bf16, frag-native LDS ----
  // write off = ks*1024 + hi*512 + col*16 + j0*2, XOR'd to spread write banks;
  // the same XOR (fn of ks, hi only) is applied on the read side.
  for (int it = 0; it < 16; ++it){
    int id  = it * 256 + threadIdx.x;       // [0, 4096)
    int col = id >> 7;                      // 0..31
    int k0  = (id & 127) * 4;               // 0..508
    int cg  = col_base + col;
    float4 v = make_float4(0.f, 0.f, 0.f, 0.f);
    if (cg < col_end) v = *(const float4*)(weight + (size_t)cg * D + k0);
    unsigned int lo = (unsigned int)f2bf(v.x) | ((unsigned int)f2bf(v.y) << 16);
    unsigned int hi2 = (unsigned int)f2bf(v.z) | ((unsigned int)f2bf(v.w) << 16);
    int ks = k0 >> 4, bhi = (k0 >> 3) & 1, j0 = k0 & 7;
    int off = ks * 1024 + bhi * 512 + col * 16 + j0 * 2;
    off ^= ((ks & 3) << 5) ^ (bhi << 4);
    uint2 pk; pk.x = lo; pk.y = hi2;
    *(uint2*)((char*)Bs + off) = pk;
  }
  __syncthreads();

  int wave  = threadIdx.x >> 6;
  int lane  = threadIdx.x & 63;
  int laneM = lane & 31;
  int hi    = lane >> 5;
  int M = padded[seg];
  const unsigned short* fseg = frags + (size_t)seg * 2048 * 512;
  const int*  lists_seg = lists + seg * 2048;
  float*      acc_seg   = acc_out + seg * 2049;

  int cg0 = col_base + laneM;
  float b0v = (cg0 < col_end && !is_root(cg0)) ? bias[cg0] : -INFINITY;

  const char* bsc = (const char*)Bs;
  int roff = (lane * 16) ^ (hi << 4);   // read base (lane part of XOR folded in)

  for (int m0 = 0; m0 < M; m0 += 256){
    int r0 = m0 + wave * 64;
    f32x16 acc0, acc1;
    #pragma unroll
    for (int i = 0; i < 16; ++i){ acc0[i] = 0.f; acc1[i] = 0.f; }

    const unsigned short* pa0 = fseg + (size_t)(r0 >> 5) * 16384 + (size_t)lane * 8;
    const unsigned short* pa1 = pa0 + 16384;

    bf16x8 A0[4], A1[4], B0[4];
    #pragma unroll
    for (int d = 0; d < 4; ++d){
      A0[d] = *(const bf16x8*)(pa0 + d * 512);
      A1[d] = *(const bf16x8*)(pa1 + d * 512);
      B0[d] = *(const bf16x8*)(bsc + (d * 1024 + (roff ^ ((d & 3) << 5))));
    }
    #pragma unroll
    for (int ks = 0; ks < 32; ++ks){
      int s = ks & 3;                 // static after full unroll
      bf16x8 a0 = A0[s], a1 = A1[s], b0 = B0[s];
      if (ks < 28){
        int kn = ks + 4;
        A0[s] = *(const bf16x8*)(pa0 + kn * 512);
        A1[s] = *(const bf16x8*)(pa1 + kn * 512);
        B0[s] = *(const bf16x8*)(bsc + (kn * 1024 + (roff ^ ((kn & 3) << 5))));
      }
      acc0 = __builtin_amdgcn_mfma_f32_32x32x16_bf16(a0, b0, acc0, 0, 0, 0);
      acc1 = __builtin_amdgcn_mfma_f32_32x32x16_bf16(a1, b0, acc1, 0, 0, 0);
    }
    epi32(acc0, b0v, r0,      hi, laneM, lists_seg, acc_seg);
    epi32(acc1, b0v, r0 + 32, hi, laneM, lists_seg, acc_seg);
  }
}

// ---------------------------------------------------------------------------
// K6: finalize NLL per token.
// ---------------------------------------------------------------------------
__global__ void k_finalize(const float* __restrict__ accs,   // [4][2049]
                           const float* __restrict__ cl,     // [2048][3]
                           const float* __restrict__ tgt,
                           const int*   __restrict__ target,
                           float* __restrict__ out)
{
  int n = blockIdx.x * blockDim.x + threadIdx.x;
  if (n >= NTOK) return;
  int c = cluster_of(target[n]);
  float e0 = __expf(cl[n*3+0]), e1 = __expf(cl[n*3+1]), e2 = __expf(cl[n*3+2]);
  float head_lse = __logf(accs[n] + e0 + e1 + e2);
  float nll;
  if (c == 0){
    nll = head_lse - tgt[n];
  } else {
    float tail_lse = __logf(accs[c * 2049 + n]);
    nll = head_lse + tail_lse - cl[n*3 + (3 - c)] - tgt[n];
  }
  out[n] = nll;
}

extern "C" void kernel_launch(void* const* d_in, const int* in_sizes, int n_in,
                              void* d_out, int out_size, void* d_ws, size_t ws_size,
                              hipStream_t stream)
{
  (void)in_sizes; (void)n_in; (void)out_size; (void)ws_size;
  const float* hidden = (const float*)d_in[0];
  const float* weight = (const float*)d_in[1];
  const float* bias   = (const float*)d_in[2];
  const float* cw     = (const float*)d_in[3];
  const float* cb     = (const float*)d_in[4];
  const int*   target = (const int*)d_in[5];
  float* out = (float*)d_out;
  char*  ws  = (char*)d_ws;

  unsigned short* frags = (unsigned short*)(ws + WS_FRAGS);
  int*   lists   = (int*)(ws + WS_LISTS);
  float* acc     = (float*)(ws + WS_ACC);
  int*   cursors = (int*)(ws + WS_CUR);
  int*   padded  = (int*)(ws + WS_PAD);
  float* cl      = (float*)(ws + WS_CL);
  float* tgt     = (float*)(ws + WS_TGT);

  hipMemsetAsync(ws + WS_ACC, 0, (WS_CUR + 16u) - WS_ACC, stream);

  k_token_logits<<<512, 256, 0, stream>>>(hidden, weight, bias, cw, cb, target, cl, tgt);
  k_build_lists <<<8,   256, 0, stream>>>(target, lists, cursors);
  k_pad_lists   <<<1,   256, 0, stream>>>(lists, cursors, padded);
  k_build_frags <<<2048,256, 0, stream>>>(hidden, lists, padded, frags);
  k_gemm        <<<3127,256, 0, stream>>>(frags, weight, bias, lists, padded, acc);
  k_finalize    <<<8,   256, 0, stream>>>(acc, cl, tgt, target, out);
}

// Round 4
// 2356.474 us; speedup vs baseline: 1.0721x; 1.0721x over previous
//
#include <hip/hip_runtime.h>
#include <math.h>

#define NTOK   2048
#define D      512
#define NV     100000

typedef __attribute__((ext_vector_type(8)))  short bf16x8;
typedef __attribute__((ext_vector_type(16))) float f32x16;

// ---- workspace layout (bytes) ----
#define WS_FRAGS 0u          // 4 segs * 2048 rows * 512 * 2B = 8,388,608
#define WS_LISTS 8388608u    // 4 * 2048 * 4B
#define WS_ACC   8421376u    // 4 * 2049 * 4B = 32784  (zeroed each call, + cursors)
#define WS_CUR   8454160u    // 4 * 4
#define WS_PAD   8454176u    // 4 * 4
#define WS_CL    8454192u    // 2048 * 3 * 4B
#define WS_TGT   8478768u    // 2048 * 4B

__device__ __forceinline__ int cluster_of(int t){
  return (t < 10000) ? 0 : (t < 20000) ? 1 : (t < 50000) ? 2 : 3;
}
__device__ __forceinline__ bool is_root(int c){
  return c==5 || c==17 || c==123 || c==10005 || c==20007 || c==50011;
}
// f32 -> bf16 round-to-nearest-even
__device__ __forceinline__ unsigned short f2bf(float f){
  unsigned int u = __float_as_uint(f);
  u += 0x7fffu + ((u >> 16) & 1u);
  return (unsigned short)(u >> 16);
}

// ---------------------------------------------------------------------------
// K1: per-token cluster logits (3 dots) + exact-f32 target logit. 1 wave/token.
// ---------------------------------------------------------------------------
__global__ void k_token_logits(const float* __restrict__ hidden,
                               const float* __restrict__ weight,
                               const float* __restrict__ bias,
                               const float* __restrict__ cw,
                               const float* __restrict__ cb,
                               const int*   __restrict__ target,
                               float* __restrict__ cl_out,   // [2048][3]
                               float* __restrict__ tgt_out)  // [2048]
{
  int wave = threadIdx.x >> 6;
  int lane = threadIdx.x & 63;
  int n = blockIdx.x * 4 + wave;
  if (n >= NTOK) return;
  const float* h = hidden + (size_t)n * D + lane * 8;
  int t = target[n];
  const float* wt = weight + (size_t)t * D + lane * 8;
  float hv[8];
  #pragma unroll
  for (int i = 0; i < 8; ++i) hv[i] = h[i];
  float acc[4] = {0.f, 0.f, 0.f, 0.f};
  #pragma unroll
  for (int j = 0; j < 3; ++j){
    const float* cwj = cw + j * D + lane * 8;
    float s = 0.f;
    #pragma unroll
    for (int i = 0; i < 8; ++i) s += hv[i] * cwj[i];
    acc[j] = s;
  }
  {
    float s = 0.f;
    #pragma unroll
    for (int i = 0; i < 8; ++i) s += hv[i] * wt[i];
    acc[3] = s;
  }
  #pragma unroll
  for (int m = 1; m < 64; m <<= 1){
    #pragma unroll
    for (int j = 0; j < 4; ++j) acc[j] += __shfl_xor(acc[j], m, 64);
  }
  if (lane == 0){
    cl_out[n*3+0] = acc[0] + cb[0];
    cl_out[n*3+1] = acc[1] + cb[1];
    cl_out[n*3+2] = acc[2] + cb[2];
    float tg = acc[3] + bias[t];
    if (is_root(t)) tg = -INFINITY;
    tgt_out[n] = tg;
  }
}

// ---------------------------------------------------------------------------
// K2: build per-segment token lists. seg0 = identity; tails via atomic cursor.
// ---------------------------------------------------------------------------
__global__ void k_build_lists(const int* __restrict__ target,
                              int* __restrict__ lists, int* __restrict__ cursors)
{
  int n = blockIdx.x * blockDim.x + threadIdx.x;
  if (n >= NTOK) return;
  lists[n] = n;  // seg 0 identity
  int c = cluster_of(target[n]);
  if (c > 0){
    int pos = atomicAdd(cursors + c, 1);
    lists[c * 2048 + pos] = n;
  }
}

// ---------------------------------------------------------------------------
// K3: pad lists to multiples of 256 with sentinel token (=NTOK), write counts.
// ---------------------------------------------------------------------------
__global__ void k_pad_lists(int* __restrict__ lists, const int* __restrict__ cursors,
                            int* __restrict__ padded)
{
  if (threadIdx.x == 0) padded[0] = NTOK;
  for (int s = 1; s < 4; ++s){
    int c = cursors[s];
    int p = (c + 255) & ~255;
    if (threadIdx.x == 0) padded[s] = p;
    for (int i = c + threadIdx.x; i < p; i += blockDim.x)
      lists[s * 2048 + i] = NTOK;
  }
}

// ---------------------------------------------------------------------------
// K4: build bf16 A-fragments in MFMA-native layout per segment.
// elem offset = ((mf*32 + ks)*64 + lane)*8 ; row = mf*32+(lane&31),
// k = ks*16 + (lane>>5)*8 + j  (same k-convention as B).
// ---------------------------------------------------------------------------
__global__ void k_build_frags(const float* __restrict__ hidden,
                              const int*   __restrict__ lists,
                              const int*   __restrict__ padded,
                              unsigned short* __restrict__ frags)
{
  int tg   = blockIdx.x * 256 + threadIdx.x;   // [0, 4*131072)
  int seg  = tg >> 17;
  int s    = tg & 131071;
  int lane = s & 63;
  int ks   = (s >> 6) & 31;
  int mf   = s >> 11;
  int row  = mf * 32 + (lane & 31);
  if (row >= padded[seg]) return;
  int token = lists[seg * 2048 + row];
  unsigned int w[4];
  if (token < NTOK){
    const float* h = hidden + (size_t)token * D + ks * 16 + (lane >> 5) * 8;
    #pragma unroll
    for (int i = 0; i < 4; ++i){
      unsigned short lo = f2bf(h[2*i]);
      unsigned short hi = f2bf(h[2*i+1]);
      w[i] = (unsigned int)lo | ((unsigned int)hi << 16);
    }
  } else {
    w[0] = w[1] = w[2] = w[3] = 0u;
  }
  size_t off = ((size_t)seg * 2048 * 512) + (((size_t)(mf * 32 + ks)) * 64 + lane) * 8;
  uint4 val; val.x = w[0]; val.y = w[1]; val.z = w[2]; val.w = w[3];
  *(uint4*)(frags + off) = val;
}

// ---------------------------------------------------------------------------
// K5: Σexp GEMM, 32-col strips, B frag-native in LDS (proven 0-conflict).
// Plain fully-unrolled K-loop (no register arrays -> no spill; compiler
// hoists loads up to the VGPR budget). Epilogue: LDS transpose-reduce
// (replaces the 80-shuffle butterfly): wave writes exp values to a private
// 32x36 f32 scratch tile, lanes re-read rows as float4, one shfl_xor(32)
// completes the row sum, 32 atomics/wave.
// ---------------------------------------------------------------------------
__device__ __forceinline__ void epi_lds(const f32x16& a, float b0v, int rbase,
                                        int hi, int lane, float* __restrict__ sc_w,
                                        const int* __restrict__ lists_seg,
                                        float* __restrict__ acc_seg)
{
  int laneM = lane & 31;
  // write phase: 16 rows x (col=laneM); stride 36 -> conflict-free
  #pragma unroll
  for (int r = 0; r < 16; ++r){
    int row = (r & 3) + 8 * (r >> 2) + 4 * hi;   // verified C/D layout
    sc_w[row * 36 + laneM] = __expf(a[r] + b0v);
  }
  // read phase: lane -> row (lane&31), col-half (lane>>5). 4x float4.
  const float4* p = (const float4*)(sc_w + (lane & 31) * 36 + (lane >> 5) * 16);
  float4 v0 = p[0], v1 = p[1], v2 = p[2], v3 = p[3];
  float s = ((v0.x + v0.y) + (v0.z + v0.w)) + ((v1.x + v1.y) + (v1.z + v1.w))
          + ((v2.x + v2.y) + (v2.z + v2.w)) + ((v3.x + v3.y) + (v3.z + v3.w));
  s += __shfl_xor(s, 32, 64);                    // combine col halves
  if (lane < 32){
    int row = rbase + (lane & 31);
    atomicAdd(acc_seg + lists_seg[row], s);
  }
}

__global__ __launch_bounds__(256, 3)
void k_gemm(const unsigned short* __restrict__ frags,
            const float* __restrict__ weight,
            const float* __restrict__ bias,
            const int*   __restrict__ lists,
            const int*   __restrict__ padded,
            float* __restrict__ acc_out)       // [4][2049]
{
  __shared__ unsigned short Bs[512 * 32];      // 32 KB
  __shared__ float sc[4][32 * 36];             // 18 KB epilogue scratch (per wave)

  int bid = blockIdx.x;
  int seg, strip0, colstart, colend;
  if      (bid < 313) { seg = 0; strip0 = 0;    colstart = 0;     colend = 10000;  }
  else if (bid < 626) { seg = 1; strip0 = 313;  colstart = 10000; colend = 20000;  }
  else if (bid < 1564){ seg = 2; strip0 = 626;  colstart = 20000; colend = 50000;  }
  else                { seg = 3; strip0 = 1564; colstart = 50000; colend = 100000; }
  int col_base = colstart + (bid - strip0) * 32;
  int col_end  = min(col_base + 32, colend);

  // ---- load B strip: 32 cols x 512 k, f32 -> bf16, frag-native LDS ----
  for (int it = 0; it < 16; ++it){
    int id  = it * 256 + threadIdx.x;       // [0, 4096)
    int col = id >> 7;                      // 0..31
    int k0  = (id & 127) * 4;               // 0..508
    int cg  = col_base + col;
    float4 v = make_float4(0.f, 0.f, 0.f, 0.f);
    if (cg < col_end) v = *(const float4*)(weight + (size_t)cg * D + k0);
    unsigned int lo  = (unsigned int)f2bf(v.x) | ((unsigned int)f2bf(v.y) << 16);
    unsigned int hi2 = (unsigned int)f2bf(v.z) | ((unsigned int)f2bf(v.w) << 16);
    int ks = k0 >> 4, bhi = (k0 >> 3) & 1, j0 = k0 & 7;
    int off = ks * 1024 + bhi * 512 + col * 16 + j0 * 2;
    off ^= ((ks & 3) << 5) ^ (bhi << 4);
    uint2 pk; pk.x = lo; pk.y = hi2;
    *(uint2*)((char*)Bs + off) = pk;
  }
  __syncthreads();

  int wave  = threadIdx.x >> 6;
  int lane  = threadIdx.x & 63;
  int laneM = lane & 31;
  int hi    = lane >> 5;
  int M = padded[seg];
  const unsigned short* fseg = frags + (size_t)seg * 2048 * 512;
  const int*  lists_seg = lists + seg * 2048;
  float*      acc_seg   = acc_out + seg * 2049;
  float*      sc_w      = sc[wave];

  int cg0 = col_base + laneM;
  float b0v = (cg0 < col_end && !is_root(cg0)) ? bias[cg0] : -INFINITY;

  const char* bsc = (const char*)Bs;
  int roff = (lane * 16) ^ (hi << 4);   // read base; (ks&3)<<5 XOR per iter

  for (int m0 = 0; m0 < M; m0 += 256){
    int r0 = m0 + wave * 64;
    f32x16 acc0, acc1;
    #pragma unroll
    for (int i = 0; i < 16; ++i){ acc0[i] = 0.f; acc1[i] = 0.f; }

    const unsigned short* pa0 = fseg + (size_t)(r0 >> 5) * 16384 + (size_t)lane * 8;
    const unsigned short* pa1 = pa0 + 16384;

    #pragma unroll
    for (int ks = 0; ks < 32; ++ks){
      bf16x8 a0 = *(const bf16x8*)(pa0 + ks * 512);
      bf16x8 a1 = *(const bf16x8*)(pa1 + ks * 512);
      bf16x8 b0 = *(const bf16x8*)(bsc + (ks * 1024 + (roff ^ ((ks & 3) << 5))));
      acc0 = __builtin_amdgcn_mfma_f32_32x32x16_bf16(a0, b0, acc0, 0, 0, 0);
      acc1 = __builtin_amdgcn_mfma_f32_32x32x16_bf16(a1, b0, acc1, 0, 0, 0);
    }
    epi_lds(acc0, b0v, r0,      hi, lane, sc_w, lists_seg, acc_seg);
    epi_lds(acc1, b0v, r0 + 32, hi, lane, sc_w, lists_seg, acc_seg);
  }
}

// ---------------------------------------------------------------------------
// K6: finalize NLL per token.
// ---------------------------------------------------------------------------
__global__ void k_finalize(const float* __restrict__ accs,   // [4][2049]
                           const float* __restrict__ cl,     // [2048][3]
                           const float* __restrict__ tgt,
                           const int*   __restrict__ target,
                           float* __restrict__ out)
{
  int n = blockIdx.x * blockDim.x + threadIdx.x;
  if (n >= NTOK) return;
  int c = cluster_of(target[n]);
  float e0 = __expf(cl[n*3+0]), e1 = __expf(cl[n*3+1]), e2 = __expf(cl[n*3+2]);
  float head_lse = __logf(accs[n] + e0 + e1 + e2);
  float nll;
  if (c == 0){
    nll = head_lse - tgt[n];
  } else {
    float tail_lse = __logf(accs[c * 2049 + n]);
    nll = head_lse + tail_lse - cl[n*3 + (3 - c)] - tgt[n];
  }
  out[n] = nll;
}

extern "C" void kernel_launch(void* const* d_in, const int* in_sizes, int n_in,
                              void* d_out, int out_size, void* d_ws, size_t ws_size,
                              hipStream_t stream)
{
  (void)in_sizes; (void)n_in; (void)out_size; (void)ws_size;
  const float* hidden = (const float*)d_in[0];
  const float* weight = (const float*)d_in[1];
  const float* bias   = (const float*)d_in[2];
  const float* cw     = (const float*)d_in[3];
  const float* cb     = (const float*)d_in[4];
  const int*   target = (const int*)d_in[5];
  float* out = (float*)d_out;
  char*  ws  = (char*)d_ws;

  unsigned short* frags = (unsigned short*)(ws + WS_FRAGS);
  int*   lists   = (int*)(ws + WS_LISTS);
  float* acc     = (float*)(ws + WS_ACC);
  int*   cursors = (int*)(ws + WS_CUR);
  int*   padded  = (int*)(ws + WS_PAD);
  float* cl      = (float*)(ws + WS_CL);
  float* tgt     = (float*)(ws + WS_TGT);

  hipMemsetAsync(ws + WS_ACC, 0, (WS_CUR + 16u) - WS_ACC, stream);

  k_token_logits<<<512, 256, 0, stream>>>(hidden, weight, bias, cw, cb, target, cl, tgt);
  k_build_lists <<<8,   256, 0, stream>>>(target, lists, cursors);
  k_pad_lists   <<<1,   256, 0, stream>>>(lists, cursors, padded);
  k_build_frags <<<2048,256, 0, stream>>>(hidden, lists, padded, frags);
  k_gemm        <<<3127,256, 0, stream>>>(frags, weight, bias, lists, padded, acc);
  k_finalize    <<<8,   256, 0, stream>>>(acc, cl, tgt, target, out);
}

// Round 5
// 371.349 us; speedup vs baseline: 6.8030x; 6.3457x over previous
//
#include <hip/hip_runtime.h>
#include <math.h>

#define NTOK   2048
#define D      512
#define NV     100000

typedef __attribute__((ext_vector_type(8)))  short bf16x8;
typedef __attribute__((ext_vector_type(16))) float f32x16;

// ---- strip geometry: 128 cols/block, 4x 32-col LDS chunks ----
// seg strips: 79, 79, 235, 391  (bases 0, 79, 158, 393; total 784)

// ---- workspace layout (bytes) ----
#define WS_FRAGS 0u           // 4 segs * 2048 * 512 * 2B = 8,388,608
#define WS_LISTS 8388608u     // 4 * 2048 * 4B = 32,768
#define WS_PART  8421376u     // 784 * 2048 * 4B = 6,422,528
#define WS_CUR   14843904u    // 16
#define WS_PAD   14843920u    // 16
#define WS_CL    14843936u    // 2048*3*4 = 24,576
#define WS_TGT   14868512u    // 2048*4   = 8,192
#define WS_ACC   14876704u    // 4*2049*4 = 32,784  (end 14,909,488)

__device__ __forceinline__ int cluster_of(int t){
  return (t < 10000) ? 0 : (t < 20000) ? 1 : (t < 50000) ? 2 : 3;
}
__device__ __forceinline__ bool is_root(int c){
  return c==5 || c==17 || c==123 || c==10005 || c==20007 || c==50011;
}
// f32 -> bf16 round-to-nearest-even
__device__ __forceinline__ unsigned short f2bf(float f){
  unsigned int u = __float_as_uint(f);
  u += 0x7fffu + ((u >> 16) & 1u);
  return (unsigned short)(u >> 16);
}

// ---------------------------------------------------------------------------
// K1: per-token cluster logits (3 dots) + exact-f32 target logit. 1 wave/token.
// ---------------------------------------------------------------------------
__global__ void k_token_logits(const float* __restrict__ hidden,
                               const float* __restrict__ weight,
                               const float* __restrict__ bias,
                               const float* __restrict__ cw,
                               const float* __restrict__ cb,
                               const int*   __restrict__ target,
                               float* __restrict__ cl_out,   // [2048][3]
                               float* __restrict__ tgt_out)  // [2048]
{
  int wave = threadIdx.x >> 6;
  int lane = threadIdx.x & 63;
  int n = blockIdx.x * 4 + wave;
  if (n >= NTOK) return;
  const float* h = hidden + (size_t)n * D + lane * 8;
  int t = target[n];
  const float* wt = weight + (size_t)t * D + lane * 8;
  float hv[8];
  #pragma unroll
  for (int i = 0; i < 8; ++i) hv[i] = h[i];
  float acc[4] = {0.f, 0.f, 0.f, 0.f};
  #pragma unroll
  for (int j = 0; j < 3; ++j){
    const float* cwj = cw + j * D + lane * 8;
    float s = 0.f;
    #pragma unroll
    for (int i = 0; i < 8; ++i) s += hv[i] * cwj[i];
    acc[j] = s;
  }
  {
    float s = 0.f;
    #pragma unroll
    for (int i = 0; i < 8; ++i) s += hv[i] * wt[i];
    acc[3] = s;
  }
  #pragma unroll
  for (int m = 1; m < 64; m <<= 1){
    #pragma unroll
    for (int j = 0; j < 4; ++j) acc[j] += __shfl_xor(acc[j], m, 64);
  }
  if (lane == 0){
    cl_out[n*3+0] = acc[0] + cb[0];
    cl_out[n*3+1] = acc[1] + cb[1];
    cl_out[n*3+2] = acc[2] + cb[2];
    float tg = acc[3] + bias[t];
    if (is_root(t)) tg = -INFINITY;
    tgt_out[n] = tg;
  }
}

// ---------------------------------------------------------------------------
// K2: build per-segment token lists. seg0 = identity; tails via atomic cursor.
// ---------------------------------------------------------------------------
__global__ void k_build_lists(const int* __restrict__ target,
                              int* __restrict__ lists, int* __restrict__ cursors)
{
  int n = blockIdx.x * blockDim.x + threadIdx.x;
  if (n >= NTOK) return;
  lists[n] = n;  // seg 0 identity
  int c = cluster_of(target[n]);
  if (c > 0){
    int pos = atomicAdd(cursors + c, 1);
    lists[c * 2048 + pos] = n;
  }
}

// ---------------------------------------------------------------------------
// K3: pad lists to multiples of 256 with sentinel token (=NTOK), write counts.
// ---------------------------------------------------------------------------
__global__ void k_pad_lists(int* __restrict__ lists, const int* __restrict__ cursors,
                            int* __restrict__ padded)
{
  if (threadIdx.x == 0) padded[0] = NTOK;
  for (int s = 1; s < 4; ++s){
    int c = cursors[s];
    int p = (c + 255) & ~255;
    if (threadIdx.x == 0) padded[s] = p;
    for (int i = c + threadIdx.x; i < p; i += blockDim.x)
      lists[s * 2048 + i] = NTOK;
  }
}

// ---------------------------------------------------------------------------
// K4: build bf16 A-fragments in MFMA-native layout per segment.
// elem offset = ((mf*32 + ks)*64 + lane)*8 ; row = mf*32+(lane&31),
// k = ks*16 + (lane>>5)*8 + j  (same k-convention as B).
// ---------------------------------------------------------------------------
__global__ void k_build_frags(const float* __restrict__ hidden,
                              const int*   __restrict__ lists,
                              const int*   __restrict__ padded,
                              unsigned short* __restrict__ frags)
{
  int tg   = blockIdx.x * 256 + threadIdx.x;   // [0, 4*131072)
  int seg  = tg >> 17;
  int s    = tg & 131071;
  int lane = s & 63;
  int ks   = (s >> 6) & 31;
  int mf   = s >> 11;
  int row  = mf * 32 + (lane & 31);
  if (row >= padded[seg]) return;
  int token = lists[seg * 2048 + row];
  unsigned int w[4];
  if (token < NTOK){
    const float* h = hidden + (size_t)token * D + ks * 16 + (lane >> 5) * 8;
    #pragma unroll
    for (int i = 0; i < 4; ++i){
      unsigned short lo = f2bf(h[2*i]);
      unsigned short hi = f2bf(h[2*i+1]);
      w[i] = (unsigned int)lo | ((unsigned int)hi << 16);
    }
  } else {
    w[0] = w[1] = w[2] = w[3] = 0u;
  }
  size_t off = ((size_t)seg * 2048 * 512) + (((size_t)(mf * 32 + ks)) * 64 + lane) * 8;
  uint4 val; val.x = w[0]; val.y = w[1]; val.z = w[2]; val.w = w[3];
  *(uint4*)(frags + off) = val;
}

// ---------------------------------------------------------------------------
// K5: Σexp GEMM, 128-col strips (4 x 32-col LDS chunks). NO global atomics:
// per-block LDS row-accumulator, stored once as non-atomic coalesced partials.
// B frag-native in LDS (0-conflict proven). Epilogue: LDS transpose-reduce.
// ---------------------------------------------------------------------------
__device__ __forceinline__ void epi_lds(const f32x16& a, float b0v, int r0,
                                        int hi, int lane, float* __restrict__ sc_w,
                                        float* __restrict__ racc)
{
  int laneM = lane & 31;
  #pragma unroll
  for (int r = 0; r < 16; ++r){
    int row = (r & 3) + 8 * (r >> 2) + 4 * hi;   // verified C/D layout
    sc_w[row * 36 + laneM] = __expf(a[r] + b0v);
  }
  const float4* p = (const float4*)(sc_w + (lane & 31) * 36 + (lane >> 5) * 16);
  float4 v0 = p[0], v1 = p[1], v2 = p[2], v3 = p[3];
  float s = ((v0.x + v0.y) + (v0.z + v0.w)) + ((v1.x + v1.y) + (v1.z + v1.w))
          + ((v2.x + v2.y) + (v2.z + v2.w)) + ((v3.x + v3.y) + (v3.z + v3.w));
  s += __shfl_xor(s, 32, 64);                    // combine col halves
  if (lane < 32) racc[r0 + lane] += s;           // wave-private rows: no race
}

__global__ __launch_bounds__(256, 2)
void k_gemm(const unsigned short* __restrict__ frags,
            const float* __restrict__ weight,
            const float* __restrict__ bias,
            const int*   __restrict__ padded,
            float* __restrict__ partials)       // [784][2048]
{
  __shared__ unsigned short Bs[512 * 32];      // 32 KB
  __shared__ float sc[4][32 * 36];             // 18 KB epilogue scratch
  __shared__ float racc[2048];                 // 8 KB row accumulator

  int bid = blockIdx.x;
  int seg, strip0, colstart, colend;
  if      (bid < 79) { seg = 0; strip0 = 0;   colstart = 0;     colend = 10000;  }
  else if (bid < 158){ seg = 1; strip0 = 79;  colstart = 10000; colend = 20000;  }
  else if (bid < 393){ seg = 2; strip0 = 158; colstart = 20000; colend = 50000;  }
  else               { seg = 3; strip0 = 393; colstart = 50000; colend = 100000; }
  int col_base = colstart + (bid - strip0) * 128;

  int wave  = threadIdx.x >> 6;
  int lane  = threadIdx.x & 63;
  int laneM = lane & 31;
  int hi    = lane >> 5;
  int M = padded[seg];
  const unsigned short* fseg = frags + (size_t)seg * 2048 * 512;
  float* sc_w = sc[wave];

  for (int r = threadIdx.x; r < 2048; r += 256) racc[r] = 0.f;

  const char* bsc = (const char*)Bs;
  int roff = (lane * 16) ^ (hi << 4);   // B read base; (ks&3)<<5 XOR per iter

  for (int chunk = 0; chunk < 4; ++chunk){
    int cb = col_base + chunk * 32;
    // ---- load B chunk: 32 cols x 512 k, f32 -> bf16, frag-native LDS ----
    for (int it = 0; it < 16; ++it){
      int id  = it * 256 + threadIdx.x;       // [0, 4096)
      int col = id >> 7;                      // 0..31
      int k0  = (id & 127) * 4;               // 0..508
      int cg  = cb + col;
      float4 v = make_float4(0.f, 0.f, 0.f, 0.f);
      if (cg < colend) v = *(const float4*)(weight + (size_t)cg * D + k0);
      unsigned int lo  = (unsigned int)f2bf(v.x) | ((unsigned int)f2bf(v.y) << 16);
      unsigned int hi2 = (unsigned int)f2bf(v.z) | ((unsigned int)f2bf(v.w) << 16);
      int ks = k0 >> 4, bhi = (k0 >> 3) & 1, j0 = k0 & 7;
      int off = ks * 1024 + bhi * 512 + col * 16 + j0 * 2;
      off ^= ((ks & 3) << 5) ^ (bhi << 4);
      uint2 pk; pk.x = lo; pk.y = hi2;
      *(uint2*)((char*)Bs + off) = pk;
    }
    __syncthreads();   // B ready (and racc zeroed, first iteration)

    int cg0 = cb + laneM;
    float b0v = (cg0 < colend && !is_root(cg0)) ? bias[cg0] : -INFINITY;

    for (int m0 = 0; m0 < M; m0 += 256){
      int r0 = m0 + wave * 64;
      f32x16 acc0, acc1;
      #pragma unroll
      for (int i = 0; i < 16; ++i){ acc0[i] = 0.f; acc1[i] = 0.f; }

      const unsigned short* pa0 = fseg + (size_t)(r0 >> 5) * 16384 + (size_t)lane * 8;
      const unsigned short* pa1 = pa0 + 16384;

      #pragma unroll
      for (int ks = 0; ks < 32; ++ks){
        bf16x8 a0 = *(const bf16x8*)(pa0 + ks * 512);
        bf16x8 a1 = *(const bf16x8*)(pa1 + ks * 512);
        bf16x8 b0 = *(const bf16x8*)(bsc + (ks * 1024 + (roff ^ ((ks & 3) << 5))));
        acc0 = __builtin_amdgcn_mfma_f32_32x32x16_bf16(a0, b0, acc0, 0, 0, 0);
        acc1 = __builtin_amdgcn_mfma_f32_32x32x16_bf16(a1, b0, acc1, 0, 0, 0);
      }
      epi_lds(acc0, b0v, r0,      hi, lane, sc_w, racc);
      epi_lds(acc1, b0v, r0 + 32, hi, lane, sc_w, racc);
    }
    __syncthreads();   // all waves done with Bs before next chunk overwrites
  }

  // ---- store per-strip partial row sums (coalesced, non-atomic) ----
  for (int r = threadIdx.x; r < M; r += 256)
    partials[(size_t)bid * 2048 + r] = racc[r];
}

// ---------------------------------------------------------------------------
// K5b: reduce partials over strips of each segment, scatter via lists -> acc.
// ---------------------------------------------------------------------------
__global__ void k_reduce(const float* __restrict__ partials,
                         const int*   __restrict__ lists,
                         const int*   __restrict__ padded,
                         float* __restrict__ acc_out)     // [4][2049]
{
  int b   = blockIdx.x;          // 32 blocks: seg = b>>3, row chunk = b&7
  int seg = b >> 3;
  int row = (b & 7) * 256 + threadIdx.x;
  if (row >= padded[seg]) return;
  int base, cnt;
  if      (seg == 0){ base = 0;   cnt = 79;  }
  else if (seg == 1){ base = 79;  cnt = 79;  }
  else if (seg == 2){ base = 158; cnt = 235; }
  else              { base = 393; cnt = 391; }
  float s = 0.f;
  int j = 0;
  for (; j + 4 <= cnt; j += 4){
    s += partials[(size_t)(base + j    ) * 2048 + row];
    s += partials[(size_t)(base + j + 1) * 2048 + row];
    s += partials[(size_t)(base + j + 2) * 2048 + row];
    s += partials[(size_t)(base + j + 3) * 2048 + row];
  }
  for (; j < cnt; ++j) s += partials[(size_t)(base + j) * 2048 + row];
  int token = lists[seg * 2048 + row];
  if (token < NTOK) acc_out[seg * 2049 + token] = s;
}

// ---------------------------------------------------------------------------
// K6: finalize NLL per token.
// ---------------------------------------------------------------------------
__global__ void k_finalize(const float* __restrict__ accs,   // [4][2049]
                           const float* __restrict__ cl,     // [2048][3]
                           const float* __restrict__ tgt,
                           const int*   __restrict__ target,
                           float* __restrict__ out)
{
  int n = blockIdx.x * blockDim.x + threadIdx.x;
  if (n >= NTOK) return;
  int c = cluster_of(target[n]);
  float e0 = __expf(cl[n*3+0]), e1 = __expf(cl[n*3+1]), e2 = __expf(cl[n*3+2]);
  float head_lse = __logf(accs[n] + e0 + e1 + e2);
  float nll;
  if (c == 0){
    nll = head_lse - tgt[n];
  } else {
    float tail_lse = __logf(accs[c * 2049 + n]);
    nll = head_lse + tail_lse - cl[n*3 + (3 - c)] - tgt[n];
  }
  out[n] = nll;
}

extern "C" void kernel_launch(void* const* d_in, const int* in_sizes, int n_in,
                              void* d_out, int out_size, void* d_ws, size_t ws_size,
                              hipStream_t stream)
{
  (void)in_sizes; (void)n_in; (void)out_size; (void)ws_size;
  const float* hidden = (const float*)d_in[0];
  const float* weight = (const float*)d_in[1];
  const float* bias   = (const float*)d_in[2];
  const float* cw     = (const float*)d_in[3];
  const float* cb     = (const float*)d_in[4];
  const int*   target = (const int*)d_in[5];
  float* out = (float*)d_out;
  char*  ws  = (char*)d_ws;

  unsigned short* frags    = (unsigned short*)(ws + WS_FRAGS);
  int*   lists    = (int*)(ws + WS_LISTS);
  float* partials = (float*)(ws + WS_PART);
  int*   cursors  = (int*)(ws + WS_CUR);
  int*   padded   = (int*)(ws + WS_PAD);
  float* cl       = (float*)(ws + WS_CL);
  float* tgt      = (float*)(ws + WS_TGT);
  float* acc      = (float*)(ws + WS_ACC);

  hipMemsetAsync(ws + WS_CUR, 0, 16, stream);   // cursors only

  k_token_logits<<<512, 256, 0, stream>>>(hidden, weight, bias, cw, cb, target, cl, tgt);
  k_build_lists <<<8,   256, 0, stream>>>(target, lists, cursors);
  k_pad_lists   <<<1,   256, 0, stream>>>(lists, cursors, padded);
  k_build_frags <<<2048,256, 0, stream>>>(hidden, lists, padded, frags);
  k_gemm        <<<784, 256, 0, stream>>>(frags, weight, bias, padded, partials);
  k_reduce      <<<32,  256, 0, stream>>>(partials, lists, padded, acc);
  k_finalize    <<<8,   256, 0, stream>>>(acc, cl, tgt, target, out);
}